// Round 4
// baseline (534.127 us; speedup 1.0000x reference)
//
#include <hip/hip_runtime.h>
#include <hip/hip_bf16.h>

using bf16 = __hip_bfloat16;
typedef short bf16x8v  __attribute__((ext_vector_type(8)));
typedef float f32x16v  __attribute__((ext_vector_type(16)));

#define GLD_LDS16(g, l) __builtin_amdgcn_global_load_lds(                      \
    (const __attribute__((address_space(1))) void*)(g),                        \
    (__attribute__((address_space(3))) void*)(l), 16, 0, 0)

__device__ __forceinline__ float bflo(unsigned int u) {
  union { unsigned int i; float f; } c; c.i = u << 16; return c.f;
}
__device__ __forceinline__ float bfhi(unsigned int u) {
  union { unsigned int i; float f; } c; c.i = u & 0xffff0000u; return c.f;
}
__device__ __forceinline__ unsigned int packbf(float a, float b) {
  return (unsigned int)(__hip_bfloat16_raw(__float2bfloat16(a)).x) |
         ((unsigned int)(__hip_bfloat16_raw(__float2bfloat16(b)).x) << 16);
}
__device__ __forceinline__ unsigned short bfraw(float a) {
  return __hip_bfloat16_raw(__float2bfloat16(a)).x;
}

// ------------------------------------------------- all fp32->bf16 casts, one launch
__global__ void f2b4_all(const float* __restrict__ x,  const float* __restrict__ wk,
                         const float* __restrict__ wv, const float* __restrict__ wr,
                         const float* __restrict__ wo,
                         bf16* __restrict__ x_bf, bf16* __restrict__ wcat,
                         bf16* __restrict__ wo_bf) {
  int i = blockIdx.x * blockDim.x + threadIdx.x;
  const float* s; bf16* d; int idx;
  if (i < 6291456) { s = x; d = x_bf; idx = i; }
  else {
    int j = i - 6291456;
    int seg = j / 147456;
    idx = j - seg * 147456;
    if (seg == 0)      { s = wk; d = wcat; }
    else if (seg == 1) { s = wv; d = wcat + 589824; }
    else if (seg == 2) { s = wr; d = wcat + 1179648; }
    else               { s = wo; d = wo_bf; }
  }
  const float4 f = reinterpret_cast<const float4*>(s)[idx];
  struct B4 { bf16 a, b, c, d; };
  B4 o = { __float2bfloat16(f.x), __float2bfloat16(f.y),
           __float2bfloat16(f.z), __float2bfloat16(f.w) };
  reinterpret_cast<B4*>(d)[idx] = o;
}

// --------------------------------------------------------------- GEMM core
// R4: R0 geometry (128x128 tile, 4 waves, 64x64 wave tile, 32 KB LDS total)
// + 2-phase DOUBLE BUFFER at BK=32. R0-R3 post-mortems: perf tracks
// occupancy, not LDS-read ratio -> wall is the per-K-step vmcnt(0) drain
// (staging latency fully exposed, only ~2.5 blocks/CU to cover it).
// New loop: stage(next buf) -> ds_read+MFMA(cur buf) -> vmcnt(0)+barrier.
// Staging latency hides under compute; 1 barrier/K-step (24 total, same as
// R0's 2x12). LDS unchanged at 32 KB so occupancy is preserved.
//
// BK=32 LDS layout (keeps the verified 128B-row-stride bank pattern):
// lds-row r' (64 of them, 128 B each) holds m-rows {2r', 2r'+1} x 32 k.
// 16B chunk s in [0,512): r'=s>>3, h=(s>>2)&1, slot gs=s&3;
//   m = 2r'+h, k-granule g = gs ^ (r'&3)  (source pre-swizzle, linear dest).
// Read row ra, granule gl: elem = (ra>>1)*64 + (ra&1)*32 + ((gl^((ra>>1)&3))*8)
// Bank starts over 32 lanes: 16*(ra&1) + 4*(gl^((ra>>1)&3)) -> 8 distinct
// starts {0,4,...,28}, 4 lanes each — identical distribution to R0's
// verified granule-XOR pattern.
__device__ __forceinline__ void stage32(
    const bf16* __restrict__ A, const bf16* __restrict__ W,
    bf16* lds_a, bf16* lds_b, int k0, size_t m0, int n0,
    const int srow[2], const int scol[2], int tid)
{
#pragma unroll
  for (int q = 0; q < 2; ++q) {
    GLD_LDS16(A + (m0 + srow[q]) * 768 + k0 + scol[q],
              &lds_a[(size_t)(tid + q * 256) * 8]);
    GLD_LDS16(W + ((size_t)n0 + srow[q]) * 768 + k0 + scol[q],
              &lds_b[(size_t)(tid + q * 256) * 8]);
  }
}

__device__ __forceinline__ void comp32(
    const bf16* lds_a, const bf16* lds_b, int wr, int wc, int l31, int hi,
    f32x16v acc[2][2])
{
#pragma unroll
  for (int ks = 0; ks < 2; ++ks) {             // k-steps of 16 within BK=32
    const int gl = ks * 2 + hi;                // granule = k/8
    bf16x8v av[2], bv[2];
#pragma unroll
    for (int i = 0; i < 2; ++i) {
      const int ra = wr + 32 * i + l31;
      av[i] = *(const bf16x8v*)&lds_a[(ra >> 1) * 64 + (ra & 1) * 32 +
                                      ((gl ^ ((ra >> 1) & 3)) * 8)];
    }
#pragma unroll
    for (int j = 0; j < 2; ++j) {
      const int rb = wc + 32 * j + l31;
      bv[j] = *(const bf16x8v*)&lds_b[(rb >> 1) * 64 + (rb & 1) * 32 +
                                      ((gl ^ ((rb >> 1) & 3)) * 8)];
    }
#pragma unroll
    for (int i = 0; i < 2; ++i)
#pragma unroll
      for (int j = 0; j < 2; ++j)
        acc[i][j] = __builtin_amdgcn_mfma_f32_32x32x16_bf16(bv[j], av[i], acc[i][j], 0, 0, 0);
  }
}

__device__ __forceinline__ void gemm_tile_acc(
    const bf16* __restrict__ A, const bf16* __restrict__ W,
    bf16* lds, int tid, size_t m0, int n0, f32x16v acc[2][2])
{
  bf16* const a0 = lds;                 // each buffer: 128x32 bf16 = 8 KB
  bf16* const b0 = lds + 4096;
  bf16* const a1 = lds + 8192;
  bf16* const b1 = lds + 12288;

  const int lane = tid & 63;
  const int wave = tid >> 6;
  const int l31  = lane & 31;
  const int hi   = lane >> 5;
  const int wr   = (wave >> 1) * 64;
  const int wc   = (wave & 1) * 64;

  int srow[2], scol[2];
#pragma unroll
  for (int q = 0; q < 2; ++q) {
    const int s = tid + q * 256;
    srow[q] = 2 * (s >> 3) + ((s >> 2) & 1);
    scol[q] = ((s & 3) ^ ((s >> 3) & 3)) * 8;
  }

#pragma unroll
  for (int i = 0; i < 2; ++i)
#pragma unroll
    for (int j = 0; j < 2; ++j)
#pragma unroll
      for (int r = 0; r < 16; ++r) acc[i][j][r] = 0.0f;

  // prologue: tile 0 -> buf0
  stage32(A, W, a0, b0, 0, m0, n0, srow, scol, tid);
  asm volatile("s_waitcnt vmcnt(0)" ::: "memory");
  __builtin_amdgcn_s_barrier();

  // 24 K-tiles of 32, processed in pairs (static buffer pointers)
  for (int t = 0; t < 24; t += 2) {
    // even step: compute buf0 (tile t), stage tile t+1 -> buf1
    stage32(A, W, a1, b1, (t + 1) * 32, m0, n0, srow, scol, tid);
    comp32(a0, b0, wr, wc, l31, hi, acc);
    asm volatile("s_waitcnt vmcnt(0)" ::: "memory");
    __builtin_amdgcn_s_barrier();
    // odd step: compute buf1 (tile t+1), stage tile t+2 -> buf0
    if (t < 22) {
      stage32(A, W, a0, b0, (t + 2) * 32, m0, n0, srow, scol, tid);
      comp32(a1, b1, wr, wc, l31, hi, acc);
      asm volatile("s_waitcnt vmcnt(0)" ::: "memory");
      __builtin_amdgcn_s_barrier();
    } else {
      comp32(a1, b1, wr, wc, l31, hi, acc);
    }
  }
}

// Epilogue index helpers: with swapped operands,
//   C row (m) = m0 + wr + 32*i + l31
//   C col (n) = n0 + wc + 32*j + (reg&3) + 8*(reg>>2) + 4*hi   (reg = 4*rr+q)

// Fused K/V/R GEMM. grid 4608 = chunk(4) x ntile(18) x mm(64), mm fastest
// (R0 order: L3 keeps the 12.5MB A-chunk resident across 18 n-passes; the
// R2 XCD remap RAISED fetch 112->160MB - don't).
__global__ __launch_bounds__(256) void gemm_kvr(
    const bf16* __restrict__ A, const bf16* __restrict__ Wcat,
    bf16* __restrict__ Kb, bf16* __restrict__ Vb, bf16* __restrict__ SRb)
{
  __shared__ __align__(16) bf16 lds[16384];   // 32 KB: 2 x (A 8KB + B 8KB)
  const int tid = threadIdx.x;
  const int bx = blockIdx.x;
  const int chunk = bx / 1152;
  const int rem   = bx % 1152;
  const int mm    = rem & 63;
  const int nt    = rem >> 6;
  const size_t m0 = (size_t)(chunk * 64 + mm) * 128;
  const int n0 = nt * 128;

  f32x16v acc[2][2];
  gemm_tile_acc(A, Wcat, lds, tid, m0, n0, acc);

  const int seg   = n0 / 768;
  const int ncol0 = n0 - seg * 768;
  bf16* __restrict__ dst = (seg == 0) ? Kb : (seg == 1) ? Vb : SRb;
  const int lane = tid & 63, wave = tid >> 6;
  const int l31 = lane & 31, hi = lane >> 5;
  const int wr = (wave >> 1) * 64, wc = (wave & 1) * 64;
#pragma unroll
  for (int i = 0; i < 2; ++i) {
    const size_t mrow = m0 + wr + 32 * i + l31;
#pragma unroll
    for (int j = 0; j < 2; ++j) {
      const int nb = ncol0 + wc + 32 * j + 4 * hi;
#pragma unroll
      for (int rr = 0; rr < 4; ++rr) {
        float v0 = acc[i][j][4 * rr + 0], v1 = acc[i][j][4 * rr + 1];
        float v2 = acc[i][j][4 * rr + 2], v3 = acc[i][j][4 * rr + 3];
        if (seg == 2) {
          v0 = 1.0f / (1.0f + __expf(-v0)); v1 = 1.0f / (1.0f + __expf(-v1));
          v2 = 1.0f / (1.0f + __expf(-v2)); v3 = 1.0f / (1.0f + __expf(-v3));
        }
        ushort4 pk = { bfraw(v0), bfraw(v1), bfraw(v2), bfraw(v3) };
        *(ushort4*)&dst[mrow * 768 + nb + 8 * rr] = pk;
      }
    }
  }
}

// Output GEMM: fp32 out. grid 1536 = chunk(4) x ntile(6) x mm(64).
__global__ __launch_bounds__(256) void gemm_out(
    const bf16* __restrict__ A, const bf16* __restrict__ W,
    float* __restrict__ out)
{
  __shared__ __align__(16) bf16 lds[16384];
  const int tid = threadIdx.x;
  const int bx = blockIdx.x;
  const int chunk = bx / 384;
  const int rem   = bx % 384;
  const int mm    = rem & 63;
  const int nt    = rem >> 6;
  const size_t m0 = (size_t)(chunk * 64 + mm) * 128;
  const int n0 = nt * 128;

  f32x16v acc[2][2];
  gemm_tile_acc(A, W, lds, tid, m0, n0, acc);

  const int lane = tid & 63, wave = tid >> 6;
  const int l31 = lane & 31, hi = lane >> 5;
  const int wr = (wave >> 1) * 64, wc = (wave & 1) * 64;
#pragma unroll
  for (int i = 0; i < 2; ++i) {
    const size_t mrow = m0 + wr + 32 * i + l31;
#pragma unroll
    for (int j = 0; j < 2; ++j) {
      const int nb = n0 + wc + 32 * j + 4 * hi;
#pragma unroll
      for (int rr = 0; rr < 4; ++rr) {
        float4 pk = { acc[i][j][4 * rr + 0], acc[i][j][4 * rr + 1],
                      acc[i][j][4 * rr + 2], acc[i][j][4 * rr + 3] };
        *(float4*)&out[mrow * 768 + nb + 8 * rr] = pk;
      }
    }
  }
}

// ------------------------------------------------------------ WKV chunk scan
// G=128 chunks of L=32. 4 channels/thread. State math fp32.
__global__ void wkv_phaseA(const bf16* __restrict__ K, const bf16* __restrict__ V,
                           const float* __restrict__ sd,
                           float* __restrict__ sA, float* __restrict__ sB, float* __restrict__ sP)
{
  const int idx = blockIdx.x * 256 + threadIdx.x;
  const int c4 = idx % 192;
  const int bg = idx / 192;
  const int g  = bg & 127;
  const int b  = bg >> 7;
  const int c0 = c4 * 4;
  float w[4], aa[4], bb[4], pp[4];
#pragma unroll
  for (int e = 0; e < 4; ++e) {
    w[e] = sd[c0 + e] * (1.0f / 4096.0f);
    aa[e] = 0.f; bb[e] = 0.f; pp[e] = -1e38f;
  }
  const size_t base = ((size_t)b * 4096 + (size_t)g * 32) * 768 + c0;
  const uint2* Kp = (const uint2*)(K + base);
  const uint2* Vp = (const uint2*)(V + base);
#pragma unroll 4
  for (int t = 0; t < 32; ++t) {
    const uint2 ku = Kp[(size_t)t * 192];
    const uint2 vu = Vp[(size_t)t * 192];
    const float kc[4] = { bflo(ku.x), bfhi(ku.x), bflo(ku.y), bfhi(ku.y) };
    const float vc[4] = { bflo(vu.x), bfhi(vu.x), bflo(vu.y), bfhi(vu.y) };
#pragma unroll
    for (int e = 0; e < 4; ++e) {
      const float ww2 = w[e] + pp[e];
      const float p2  = fmaxf(ww2, kc[e]);
      const float e1b = __expf(ww2 - p2);
      const float e2b = __expf(kc[e] - p2);
      aa[e] = e1b * aa[e] + e2b * vc[e];
      bb[e] = e1b * bb[e] + e2b;
      pp[e] = p2;
    }
  }
  const int o = g * 6144 + b * 768 + c0;
#pragma unroll
  for (int e = 0; e < 4; ++e) { sA[o + e] = aa[e]; sB[o + e] = bb[e]; sP[o + e] = pp[e]; }
}

// 96 blocks x 64 threads: 4x CU coverage for this latency-bound serial scan;
// explicit next-g prefetch hides load latency under the exp chain.
__global__ void wkv_phaseB(const float* __restrict__ sA, const float* __restrict__ sB,
                           const float* __restrict__ sP,
                           float* __restrict__ iA, float* __restrict__ iB, float* __restrict__ iP,
                           const float* __restrict__ sd)
{
  const int bc = blockIdx.x * 64 + threadIdx.x;     // B*C = 6144
  const int c  = bc % 768;
  const float Lw = 32.0f * (sd[c] * (1.0f / 4096.0f));
  float aa = 0.f, bb = 0.f, pp = -1e38f;
  float la = sA[bc], lb = sB[bc], lp = sP[bc];
  for (int g = 0; g < 128; ++g) {
    const int o = g * 6144 + bc;
    float la2 = 0.f, lb2 = 0.f, lp2 = 0.f;
    if (g < 127) { la2 = sA[o + 6144]; lb2 = sB[o + 6144]; lp2 = sP[o + 6144]; }
    iA[o] = aa; iB[o] = bb; iP[o] = pp;             // state BEFORE chunk g
    const float pd = pp + Lw;
    const float pn = fmaxf(pd, lp);
    const float e0 = __expf(pd - pn);
    const float e1 = __expf(lp - pn);
    aa = e0 * aa + e1 * la;
    bb = e0 * bb + e1 * lb;
    pp = pn;
    la = la2; lb = lb2; lp = lp2;
  }
}

__global__ void wkv_phaseC(const bf16* __restrict__ K, const bf16* __restrict__ V,
                           const bf16* __restrict__ SR,
                           const float* __restrict__ iA, const float* __restrict__ iB,
                           const float* __restrict__ iP,
                           const float* __restrict__ sd, const float* __restrict__ sf,
                           bf16* __restrict__ RY)
{
  const int idx = blockIdx.x * 256 + threadIdx.x;
  const int c4 = idx % 192;
  const int bg = idx / 192;
  const int g  = bg & 127;
  const int b  = bg >> 7;
  const int c0 = c4 * 4;
  const int o = g * 6144 + b * 768 + c0;
  float w[4], u[4], aa[4], bb[4], pp[4];
#pragma unroll
  for (int e = 0; e < 4; ++e) {
    w[e] = sd[c0 + e] * (1.0f / 4096.0f);
    u[e] = sf[c0 + e] * (1.0f / 4096.0f);
    aa[e] = iA[o + e]; bb[e] = iB[o + e]; pp[e] = iP[o + e];
  }
  const size_t base = ((size_t)b * 4096 + (size_t)g * 32) * 768 + c0;
  const uint2* Kp = (const uint2*)(K + base);
  const uint2* Vp = (const uint2*)(V + base);
  const uint2* Sp = (const uint2*)(SR + base);
  uint2* Rp = (uint2*)(RY + base);
#pragma unroll 4
  for (int t = 0; t < 32; ++t) {
    const uint2 ku = Kp[(size_t)t * 192];
    const uint2 vu = Vp[(size_t)t * 192];
    const uint2 su = Sp[(size_t)t * 192];
    const float kc[4] = { bflo(ku.x), bfhi(ku.x), bflo(ku.y), bfhi(ku.y) };
    const float vc[4] = { bflo(vu.x), bfhi(vu.x), bflo(vu.y), bfhi(vu.y) };
    const float sc[4] = { bflo(su.x), bfhi(su.x), bflo(su.y), bfhi(su.y) };
    float y[4];
#pragma unroll
    for (int e = 0; e < 4; ++e) {
      const float ww = u[e] + kc[e];
      const float p  = fmaxf(pp[e], ww);
      const float e1 = __expf(pp[e] - p);
      const float e2 = __expf(ww - p);
      y[e] = (e1 * aa[e] + e2 * vc[e]) / (e1 * bb[e] + e2) * sc[e];
      const float ww2 = w[e] + pp[e];
      const float p2  = fmaxf(ww2, kc[e]);
      const float e1b = __expf(ww2 - p2);
      const float e2b = __expf(kc[e] - p2);
      aa[e] = e1b * aa[e] + e2b * vc[e];
      bb[e] = e1b * bb[e] + e2b;
      pp[e] = p2;
    }
    uint2 r; r.x = packbf(y[0], y[1]); r.y = packbf(y[2], y[3]);
    Rp[(size_t)t * 192] = r;
  }
}

// ---------------------------------------------------------------------------
extern "C" void kernel_launch(void* const* d_in, const int* in_sizes, int n_in,
                              void* d_out, int out_size, void* d_ws, size_t ws_size,
                              hipStream_t stream)
{
  const float* x  = (const float*)d_in[0];
  const float* wk = (const float*)d_in[1];
  const float* wv = (const float*)d_in[2];
  const float* wr = (const float*)d_in[3];
  const float* wo = (const float*)d_in[4];
  const float* sd = (const float*)d_in[5];
  const float* sf = (const float*)d_in[6];
  float* out = (float*)d_out;

  char* ws = (char*)d_ws;
  bf16*  x_bf  = (bf16*) (ws + 0);            // 25165824 * 2
  bf16*  wcat  = (bf16*) (ws + 50331648);     // 2304x768 bf16
  bf16*  wo_bf = (bf16*) (ws + 53870592);
  bf16*  Kb    = (bf16*) (ws + 55050240);     // 25165824 * 2 each
  bf16*  Vb    = (bf16*) (ws + 105381888);
  bf16*  SRb   = (bf16*) (ws + 155713536);
  float* sumA  = (float*)(ws + 206045184);    // 128*6144 floats (3 MB) each
  float* sumB  = (float*)(ws + 209190912);
  float* sumP  = (float*)(ws + 212336640);
  float* iniA  = (float*)(ws + 215482368);
  float* iniB  = (float*)(ws + 218628096);
  float* iniP  = (float*)(ws + 221773824);
  bf16*  ry_bf = x_bf;                        // x dead after gemm_kvr -> alias

  f2b4_all<<<26880, 256, 0, stream>>>(x, wk, wv, wr, wo, x_bf, wcat, wo_bf);

  gemm_kvr<<<4608, 256, 0, stream>>>(x_bf, wcat, Kb, Vb, SRb);

  wkv_phaseA<<<768, 256, 0, stream>>>(Kb, Vb, sd, sumA, sumB, sumP);
  wkv_phaseB<<<96,  64, 0, stream>>>(sumA, sumB, sumP, iniA, iniB, iniP, sd);
  wkv_phaseC<<<768, 256, 0, stream>>>(Kb, Vb, SRb, iniA, iniB, iniP, sd, sf, ry_bf);

  gemm_out<<<1536, 256, 0, stream>>>(ry_bf, wo_bf, out);
}

// Round 5
// 498.204 us; speedup vs baseline: 1.0721x; 1.0721x over previous
//
#include <hip/hip_runtime.h>
#include <hip/hip_bf16.h>

using bf16 = __hip_bfloat16;
typedef short bf16x8v  __attribute__((ext_vector_type(8)));
typedef float f32x16v  __attribute__((ext_vector_type(16)));

#define GLD_LDS16(g, l) __builtin_amdgcn_global_load_lds(                      \
    (const __attribute__((address_space(1))) void*)(g),                        \
    (__attribute__((address_space(3))) void*)(l), 16, 0, 0)

__device__ __forceinline__ float bflo(unsigned int u) {
  union { unsigned int i; float f; } c; c.i = u << 16; return c.f;
}
__device__ __forceinline__ float bfhi(unsigned int u) {
  union { unsigned int i; float f; } c; c.i = u & 0xffff0000u; return c.f;
}
__device__ __forceinline__ unsigned int packbf(float a, float b) {
  return (unsigned int)(__hip_bfloat16_raw(__float2bfloat16(a)).x) |
         ((unsigned int)(__hip_bfloat16_raw(__float2bfloat16(b)).x) << 16);
}
__device__ __forceinline__ unsigned short bfraw(float a) {
  return __hip_bfloat16_raw(__float2bfloat16(a)).x;
}

// ------------------------------------------------- all fp32->bf16 casts, one launch
__global__ void f2b4_all(const float* __restrict__ x,  const float* __restrict__ wk,
                         const float* __restrict__ wv, const float* __restrict__ wr,
                         const float* __restrict__ wo,
                         bf16* __restrict__ x_bf, bf16* __restrict__ wcat,
                         bf16* __restrict__ wo_bf) {
  int i = blockIdx.x * blockDim.x + threadIdx.x;
  const float* s; bf16* d; int idx;
  if (i < 6291456) { s = x; d = x_bf; idx = i; }
  else {
    int j = i - 6291456;
    int seg = j / 147456;
    idx = j - seg * 147456;
    if (seg == 0)      { s = wk; d = wcat; }
    else if (seg == 1) { s = wv; d = wcat + 589824; }
    else if (seg == 2) { s = wr; d = wcat + 1179648; }
    else               { s = wo; d = wo_bf; }
  }
  const float4 f = reinterpret_cast<const float4*>(s)[idx];
  struct B4 { bf16 a, b, c, d; };
  B4 o = { __float2bfloat16(f.x), __float2bfloat16(f.y),
           __float2bfloat16(f.z), __float2bfloat16(f.w) };
  reinterpret_cast<B4*>(d)[idx] = o;
}

// --------------------------------------------------------------- GEMM core
// R5: R0's exact loop structure (128x128 tile, BK=64, single buffer,
// 2-barrier K-loop, granule-XOR swizzle, global_load_lds w=16,
// swapped-operand v_mfma_f32_32x32x16_bf16) but with 8 WAVES / 512 THREADS,
// wave tile 64x32 (was 4 waves / 64x64).
// Post-mortems R0-R4: perf tracks occupancy (31%->Mfma33; 21.6->22.7;
// 20->30; 18.6->28.5). The stall is the per-K-step staging drain; only
// cross-block wave overlap hides it (m114). R0 was VGPR-capped at 148/wave
// (84 arch + 64 acc) -> 3 waves/SIMD. Halving per-wave acc (32) and
// staging addresses (4 GLD not 8) cuts VGPR -> more waves/CU from
// independent-barrier blocks. Work per block identical.
// DON'T re-try: BK=32 dbuf (R4: VALU 40%, 222us), 256^2 8-phase (R1),
// 256x128 wave tile (R3), XCD n-major remap (R2: fetch 112->160MB).
__device__ __forceinline__ void gemm_tile_acc(
    const bf16* __restrict__ A, const bf16* __restrict__ W,
    bf16* lds_a, bf16* lds_b, int tid, size_t m0, int n0, f32x16v acc[2])
{
  const int lane = tid & 63;
  const int wave = tid >> 6;          // 0..7
  const int l31  = lane & 31;
  const int hi   = lane >> 5;
  const int wr   = (wave >> 2) * 64;  // 2 wave-rows x 64
  const int wc   = (wave & 3) * 32;   // 4 wave-cols x 32

  int srow[2], scol[2];
#pragma unroll
  for (int q = 0; q < 2; ++q) {
    const int s = tid + q * 512;
    srow[q] = s >> 3;
    scol[q] = (((s & 7) ^ (srow[q] & 7)) * 8);
  }

#pragma unroll
  for (int i = 0; i < 2; ++i)
#pragma unroll
    for (int r = 0; r < 16; ++r) acc[i][r] = 0.0f;

  for (int k0 = 0; k0 < 768; k0 += 64) {
    __syncthreads();
#pragma unroll
    for (int q = 0; q < 2; ++q)
      GLD_LDS16(A + (m0 + srow[q]) * 768 + k0 + scol[q], &lds_a[(size_t)(tid + q * 512) * 8]);
#pragma unroll
    for (int q = 0; q < 2; ++q)
      GLD_LDS16(W + (size_t)(n0 + srow[q]) * 768 + k0 + scol[q], &lds_b[(size_t)(tid + q * 512) * 8]);
    __syncthreads();

#pragma unroll
    for (int ks = 0; ks < 4; ++ks) {           // k-steps of 16 within BK=64
      const int gl = ks * 2 + hi;              // element granule = k/8 (pre-swizzle)
      bf16x8v av[2], bv;
#pragma unroll
      for (int i = 0; i < 2; ++i) {
        const int ra = wr + 32 * i + l31;
        av[i] = *(const bf16x8v*)&lds_a[ra * 64 + ((gl ^ (ra & 7)) * 8)];
      }
      {
        const int rb = wc + l31;
        bv = *(const bf16x8v*)&lds_b[rb * 64 + ((gl ^ (rb & 7)) * 8)];
      }
#pragma unroll
      for (int i = 0; i < 2; ++i)
        acc[i] = __builtin_amdgcn_mfma_f32_32x32x16_bf16(bv, av[i], acc[i], 0, 0, 0);
    }
  }
}

// Epilogue index helpers: with swapped operands,
//   C row (m) = m0 + wr + 32*i + l31
//   C col (n) = n0 + wc + (reg&3) + 8*(reg>>2) + 4*hi   (reg = 4*rr+q)

// Fused K/V/R GEMM. grid 4608 = chunk(4) x ntile(18) x mm(64), mm fastest
// (R0 order: L3 keeps the 12.5MB A-chunk resident across 18 n-passes).
__global__ __launch_bounds__(512) void gemm_kvr(
    const bf16* __restrict__ A, const bf16* __restrict__ Wcat,
    bf16* __restrict__ Kb, bf16* __restrict__ Vb, bf16* __restrict__ SRb)
{
  __shared__ __align__(16) bf16 lds_a[128 * 64];
  __shared__ __align__(16) bf16 lds_b[128 * 64];
  const int tid = threadIdx.x;
  const int bx = blockIdx.x;
  const int chunk = bx / 1152;
  const int rem   = bx % 1152;
  const int mm    = rem & 63;
  const int nt    = rem >> 6;
  const size_t m0 = (size_t)(chunk * 64 + mm) * 128;
  const int n0 = nt * 128;

  f32x16v acc[2];
  gemm_tile_acc(A, Wcat, lds_a, lds_b, tid, m0, n0, acc);

  const int seg   = n0 / 768;
  const int ncol0 = n0 - seg * 768;
  bf16* __restrict__ dst = (seg == 0) ? Kb : (seg == 1) ? Vb : SRb;
  const int lane = tid & 63, wave = tid >> 6;
  const int l31 = lane & 31, hi = lane >> 5;
  const int wr = (wave >> 2) * 64, wc = (wave & 3) * 32;
#pragma unroll
  for (int i = 0; i < 2; ++i) {
    const size_t mrow = m0 + wr + 32 * i + l31;
    const int nb = ncol0 + wc + 4 * hi;
#pragma unroll
    for (int rr = 0; rr < 4; ++rr) {
      float v0 = acc[i][4 * rr + 0], v1 = acc[i][4 * rr + 1];
      float v2 = acc[i][4 * rr + 2], v3 = acc[i][4 * rr + 3];
      if (seg == 2) {
        v0 = 1.0f / (1.0f + __expf(-v0)); v1 = 1.0f / (1.0f + __expf(-v1));
        v2 = 1.0f / (1.0f + __expf(-v2)); v3 = 1.0f / (1.0f + __expf(-v3));
      }
      ushort4 pk = { bfraw(v0), bfraw(v1), bfraw(v2), bfraw(v3) };
      *(ushort4*)&dst[mrow * 768 + nb + 8 * rr] = pk;
    }
  }
}

// Output GEMM: fp32 out. grid 1536 = chunk(4) x ntile(6) x mm(64).
__global__ __launch_bounds__(512) void gemm_out(
    const bf16* __restrict__ A, const bf16* __restrict__ W,
    float* __restrict__ out)
{
  __shared__ __align__(16) bf16 lds_a[128 * 64];
  __shared__ __align__(16) bf16 lds_b[128 * 64];
  const int tid = threadIdx.x;
  const int bx = blockIdx.x;
  const int chunk = bx / 384;
  const int rem   = bx % 384;
  const int mm    = rem & 63;
  const int nt    = rem >> 6;
  const size_t m0 = (size_t)(chunk * 64 + mm) * 128;
  const int n0 = nt * 128;

  f32x16v acc[2];
  gemm_tile_acc(A, W, lds_a, lds_b, tid, m0, n0, acc);

  const int lane = tid & 63, wave = tid >> 6;
  const int l31 = lane & 31, hi = lane >> 5;
  const int wr = (wave >> 2) * 64, wc = (wave & 3) * 32;
#pragma unroll
  for (int i = 0; i < 2; ++i) {
    const size_t mrow = m0 + wr + 32 * i + l31;
    const int nb = n0 + wc + 4 * hi;
#pragma unroll
    for (int rr = 0; rr < 4; ++rr) {
      float4 pk = { acc[i][4 * rr + 0], acc[i][4 * rr + 1],
                    acc[i][4 * rr + 2], acc[i][4 * rr + 3] };
      *(float4*)&out[mrow * 768 + nb + 8 * rr] = pk;
    }
  }
}

// ------------------------------------------------------------ WKV chunk scan
// G=128 chunks of L=32. 4 channels/thread. State math fp32.
__global__ void wkv_phaseA(const bf16* __restrict__ K, const bf16* __restrict__ V,
                           const float* __restrict__ sd,
                           float* __restrict__ sA, float* __restrict__ sB, float* __restrict__ sP)
{
  const int idx = blockIdx.x * 256 + threadIdx.x;
  const int c4 = idx % 192;
  const int bg = idx / 192;
  const int g  = bg & 127;
  const int b  = bg >> 7;
  const int c0 = c4 * 4;
  float w[4], aa[4], bb[4], pp[4];
#pragma unroll
  for (int e = 0; e < 4; ++e) {
    w[e] = sd[c0 + e] * (1.0f / 4096.0f);
    aa[e] = 0.f; bb[e] = 0.f; pp[e] = -1e38f;
  }
  const size_t base = ((size_t)b * 4096 + (size_t)g * 32) * 768 + c0;
  const uint2* Kp = (const uint2*)(K + base);
  const uint2* Vp = (const uint2*)(V + base);
#pragma unroll 4
  for (int t = 0; t < 32; ++t) {
    const uint2 ku = Kp[(size_t)t * 192];
    const uint2 vu = Vp[(size_t)t * 192];
    const float kc[4] = { bflo(ku.x), bfhi(ku.x), bflo(ku.y), bfhi(ku.y) };
    const float vc[4] = { bflo(vu.x), bfhi(vu.x), bflo(vu.y), bfhi(vu.y) };
#pragma unroll
    for (int e = 0; e < 4; ++e) {
      const float ww2 = w[e] + pp[e];
      const float p2  = fmaxf(ww2, kc[e]);
      const float e1b = __expf(ww2 - p2);
      const float e2b = __expf(kc[e] - p2);
      aa[e] = e1b * aa[e] + e2b * vc[e];
      bb[e] = e1b * bb[e] + e2b;
      pp[e] = p2;
    }
  }
  const int o = g * 6144 + b * 768 + c0;
#pragma unroll
  for (int e = 0; e < 4; ++e) { sA[o + e] = aa[e]; sB[o + e] = bb[e]; sP[o + e] = pp[e]; }
}

// R5: parallel Hillis-Steele scan over the 128 chunks (was 128 serial
// latency-exposed iterations). Element = (a, b, p, L): represents the
// affine map  acc -> acc*e^L + a*e^p  on the true (unshifted) accumulator.
// combine(left, right): pn = max(pl + Lr, pr); a = e^(pl+Lr-pn)*al +
// e^(pr-pn)*ar; L = Ll + Lr  -- associative (composition of affine maps);
// leaf g = chunk summary with L = 32*w. Exclusive prefix = state BEFORE
// chunk g (identity (0,0,-inf,0) checks out). One block per bc channel;
// gathers are uncoalesced but L2-resident (sA/sB/sP = 9 MB total).
__global__ void wkv_phaseB(const float* __restrict__ sA, const float* __restrict__ sB,
                           const float* __restrict__ sP,
                           float* __restrict__ iA, float* __restrict__ iB, float* __restrict__ iP,
                           const float* __restrict__ sd)
{
  const int bc = blockIdx.x;            // 0..6143
  const int g  = threadIdx.x;           // 0..127
  const int c  = bc % 768;
  const float Lw = 32.0f * (sd[c] * (1.0f / 4096.0f));
  __shared__ float sa[128], sb[128], sp[128], sl[128];
  const int o = g * 6144 + bc;
  float a = sA[o], b = sB[o], p = sP[o], L = Lw;
  sa[g] = a; sb[g] = b; sp[g] = p; sl[g] = L;
  __syncthreads();
#pragma unroll
  for (int d = 1; d < 128; d <<= 1) {
    float a2 = a, b2 = b, p2 = p, L2 = L;
    if (g >= d) {
      const float al = sa[g - d], bl = sb[g - d], pl = sp[g - d], Ll = sl[g - d];
      const float pn = fmaxf(pl + L, p);
      const float e0 = __expf(pl + L - pn);
      const float e1 = __expf(p - pn);
      a2 = e0 * al + e1 * a;
      b2 = e0 * bl + e1 * b;
      p2 = pn;
      L2 = Ll + L;
    }
    __syncthreads();
    sa[g] = a2; sb[g] = b2; sp[g] = p2; sl[g] = L2;
    a = a2; b = b2; p = p2; L = L2;
    __syncthreads();
  }
  float oa = 0.f, ob = 0.f, op = -1e38f;
  if (g > 0) { oa = sa[g - 1]; ob = sb[g - 1]; op = sp[g - 1]; }
  iA[o] = oa; iB[o] = ob; iP[o] = op;
}

__global__ void wkv_phaseC(const bf16* __restrict__ K, const bf16* __restrict__ V,
                           const bf16* __restrict__ SR,
                           const float* __restrict__ iA, const float* __restrict__ iB,
                           const float* __restrict__ iP,
                           const float* __restrict__ sd, const float* __restrict__ sf,
                           bf16* __restrict__ RY)
{
  const int idx = blockIdx.x * 256 + threadIdx.x;
  const int c4 = idx % 192;
  const int bg = idx / 192;
  const int g  = bg & 127;
  const int b  = bg >> 7;
  const int c0 = c4 * 4;
  const int o = g * 6144 + b * 768 + c0;
  float w[4], u[4], aa[4], bb[4], pp[4];
#pragma unroll
  for (int e = 0; e < 4; ++e) {
    w[e] = sd[c0 + e] * (1.0f / 4096.0f);
    u[e] = sf[c0 + e] * (1.0f / 4096.0f);
    aa[e] = iA[o + e]; bb[e] = iB[o + e]; pp[e] = iP[o + e];
  }
  const size_t base = ((size_t)b * 4096 + (size_t)g * 32) * 768 + c0;
  const uint2* Kp = (const uint2*)(K + base);
  const uint2* Vp = (const uint2*)(V + base);
  const uint2* Sp = (const uint2*)(SR + base);
  uint2* Rp = (uint2*)(RY + base);
#pragma unroll 4
  for (int t = 0; t < 32; ++t) {
    const uint2 ku = Kp[(size_t)t * 192];
    const uint2 vu = Vp[(size_t)t * 192];
    const uint2 su = Sp[(size_t)t * 192];
    const float kc[4] = { bflo(ku.x), bfhi(ku.x), bflo(ku.y), bfhi(ku.y) };
    const float vc[4] = { bflo(vu.x), bfhi(vu.x), bflo(vu.y), bfhi(vu.y) };
    const float sc[4] = { bflo(su.x), bfhi(su.x), bflo(su.y), bfhi(su.y) };
    float y[4];
#pragma unroll
    for (int e = 0; e < 4; ++e) {
      const float ww = u[e] + kc[e];
      const float p  = fmaxf(pp[e], ww);
      const float e1 = __expf(pp[e] - p);
      const float e2 = __expf(ww - p);
      y[e] = (e1 * aa[e] + e2 * vc[e]) / (e1 * bb[e] + e2) * sc[e];
      const float ww2 = w[e] + pp[e];
      const float p2  = fmaxf(ww2, kc[e]);
      const float e1b = __expf(ww2 - p2);
      const float e2b = __expf(kc[e] - p2);
      aa[e] = e1b * aa[e] + e2b * vc[e];
      bb[e] = e1b * bb[e] + e2b;
      pp[e] = p2;
    }
    uint2 r; r.x = packbf(y[0], y[1]); r.y = packbf(y[2], y[3]);
    Rp[(size_t)t * 192] = r;
  }
}

// ---------------------------------------------------------------------------
extern "C" void kernel_launch(void* const* d_in, const int* in_sizes, int n_in,
                              void* d_out, int out_size, void* d_ws, size_t ws_size,
                              hipStream_t stream)
{
  const float* x  = (const float*)d_in[0];
  const float* wk = (const float*)d_in[1];
  const float* wv = (const float*)d_in[2];
  const float* wr = (const float*)d_in[3];
  const float* wo = (const float*)d_in[4];
  const float* sd = (const float*)d_in[5];
  const float* sf = (const float*)d_in[6];
  float* out = (float*)d_out;

  char* ws = (char*)d_ws;
  bf16*  x_bf  = (bf16*) (ws + 0);            // 25165824 * 2
  bf16*  wcat  = (bf16*) (ws + 50331648);     // 2304x768 bf16
  bf16*  wo_bf = (bf16*) (ws + 53870592);
  bf16*  Kb    = (bf16*) (ws + 55050240);     // 25165824 * 2 each
  bf16*  Vb    = (bf16*) (ws + 105381888);
  bf16*  SRb   = (bf16*) (ws + 155713536);
  float* sumA  = (float*)(ws + 206045184);    // 128*6144 floats (3 MB) each
  float* sumB  = (float*)(ws + 209190912);
  float* sumP  = (float*)(ws + 212336640);
  float* iniA  = (float*)(ws + 215482368);
  float* iniB  = (float*)(ws + 218628096);
  float* iniP  = (float*)(ws + 221773824);
  bf16*  ry_bf = x_bf;                        // x dead after gemm_kvr -> alias

  f2b4_all<<<26880, 256, 0, stream>>>(x, wk, wv, wr, wo, x_bf, wcat, wo_bf);

  gemm_kvr<<<4608, 512, 0, stream>>>(x_bf, wcat, Kb, Vb, SRb);

  wkv_phaseA<<<768, 256, 0, stream>>>(Kb, Vb, sd, sumA, sumB, sumP);
  wkv_phaseB<<<6144, 128, 0, stream>>>(sumA, sumB, sumP, iniA, iniB, iniP, sd);
  wkv_phaseC<<<768, 256, 0, stream>>>(Kb, Vb, SRb, iniA, iniB, iniP, sd, sf, ry_bf);

  gemm_out<<<1536, 512, 0, stream>>>(ry_bf, wo_bf, out);
}

// Round 6
// 445.924 us; speedup vs baseline: 1.1978x; 1.1172x over previous
//
#include <hip/hip_runtime.h>
#include <hip/hip_bf16.h>

using bf16 = __hip_bfloat16;
typedef short bf16x8v  __attribute__((ext_vector_type(8)));
typedef float f32x16v  __attribute__((ext_vector_type(16)));

#define GLD_LDS16(g, l) __builtin_amdgcn_global_load_lds(                      \
    (const __attribute__((address_space(1))) void*)(g),                        \
    (__attribute__((address_space(3))) void*)(l), 16, 0, 0)

__device__ __forceinline__ float bflo(unsigned int u) {
  union { unsigned int i; float f; } c; c.i = u << 16; return c.f;
}
__device__ __forceinline__ float bfhi(unsigned int u) {
  union { unsigned int i; float f; } c; c.i = u & 0xffff0000u; return c.f;
}
__device__ __forceinline__ unsigned int packbf(float a, float b) {
  return (unsigned int)(__hip_bfloat16_raw(__float2bfloat16(a)).x) |
         ((unsigned int)(__hip_bfloat16_raw(__float2bfloat16(b)).x) << 16);
}
__device__ __forceinline__ unsigned short bfraw(float a) {
  return __hip_bfloat16_raw(__float2bfloat16(a)).x;
}

// ------------------------------------------------- all fp32->bf16 casts, one launch
__global__ void f2b4_all(const float* __restrict__ x,  const float* __restrict__ wk,
                         const float* __restrict__ wv, const float* __restrict__ wr,
                         const float* __restrict__ wo,
                         bf16* __restrict__ x_bf, bf16* __restrict__ wcat,
                         bf16* __restrict__ wo_bf) {
  int i = blockIdx.x * blockDim.x + threadIdx.x;
  const float* s; bf16* d; int idx;
  if (i < 6291456) { s = x; d = x_bf; idx = i; }
  else {
    int j = i - 6291456;
    int seg = j / 147456;
    idx = j - seg * 147456;
    if (seg == 0)      { s = wk; d = wcat; }
    else if (seg == 1) { s = wv; d = wcat + 589824; }
    else if (seg == 2) { s = wr; d = wcat + 1179648; }
    else               { s = wo; d = wo_bf; }
  }
  const float4 f = reinterpret_cast<const float4*>(s)[idx];
  struct B4 { bf16 a, b, c, d; };
  B4 o = { __float2bfloat16(f.x), __float2bfloat16(f.y),
           __float2bfloat16(f.z), __float2bfloat16(f.w) };
  reinterpret_cast<B4*>(d)[idx] = o;
}

// --------------------------------------------------------------- GEMM core
// R6: R5's 8-wave geometry (128x128 tile, wave tile 64x32, VGPR 36 arch,
// granule-XOR swizzle, global_load_lds w=16, swapped-operand
// v_mfma_f32_32x32x16_bf16) + BK=64 DOUBLE BUFFER, one __syncthreads per
// K-step. Theory (R0-R5 falsification chain): not LDS-BW (R3), not
// occupancy/TLP (R5: occ 62% == occ 31% perf). Wall = per-K-step serial
// {stage-issue -> vmcnt(0) drain -> compute}. Fix: stage(t+1) issued after
// barrier, compute(t) (~550cy) covers L2 latency, next barrier's implicit
// vmcnt(0) has near-zero residual (only stage(t+1) outstanding there).
// R4's dbuf failed because BK=32's compute window (~250cy) < latency and
// VALU overhead doubled; BK=64 is the untested cell.
// DON'T re-try: BK=32 dbuf (R4), 256^2 8-phase (R1), 256x128 wave tile
// (R3), XCD n-major remap (R2: fetch 112->160MB).
__device__ __forceinline__ void stg64(
    const bf16* __restrict__ A, const bf16* __restrict__ W,
    bf16* la, bf16* lb, int k0, size_t m0, int n0,
    const int srow[2], const int scol[2], int tid)
{
#pragma unroll
  for (int q = 0; q < 2; ++q) {
    GLD_LDS16(A + (m0 + srow[q]) * 768 + k0 + scol[q],
              &la[(size_t)(tid + q * 512) * 8]);
    GLD_LDS16(W + ((size_t)n0 + srow[q]) * 768 + k0 + scol[q],
              &lb[(size_t)(tid + q * 512) * 8]);
  }
}

__device__ __forceinline__ void comp64(
    const bf16* la, const bf16* lb, int wr, int wc, int l31, int hi,
    f32x16v acc[2])
{
#pragma unroll
  for (int ks = 0; ks < 4; ++ks) {           // k-steps of 16 within BK=64
    const int gl = ks * 2 + hi;              // element granule = k/8 (pre-swizzle)
    bf16x8v av[2], bv;
#pragma unroll
    for (int i = 0; i < 2; ++i) {
      const int ra = wr + 32 * i + l31;
      av[i] = *(const bf16x8v*)&la[ra * 64 + ((gl ^ (ra & 7)) * 8)];
    }
    {
      const int rb = wc + l31;
      bv = *(const bf16x8v*)&lb[rb * 64 + ((gl ^ (rb & 7)) * 8)];
    }
#pragma unroll
    for (int i = 0; i < 2; ++i)
      acc[i] = __builtin_amdgcn_mfma_f32_32x32x16_bf16(bv, av[i], acc[i], 0, 0, 0);
  }
}

__device__ __forceinline__ void gemm_tile_acc(
    const bf16* __restrict__ A, const bf16* __restrict__ W,
    bf16* lds, int tid, size_t m0, int n0, f32x16v acc[2])
{
  bf16* const a0 = lds;                 // each 128x64 bf16 = 16 KB
  bf16* const b0 = lds + 8192;
  bf16* const a1 = lds + 16384;
  bf16* const b1 = lds + 24576;

  const int lane = tid & 63;
  const int wave = tid >> 6;          // 0..7
  const int l31  = lane & 31;
  const int hi   = lane >> 5;
  const int wr   = (wave >> 2) * 64;  // 2 wave-rows x 64
  const int wc   = (wave & 3) * 32;   // 4 wave-cols x 32

  int srow[2], scol[2];
#pragma unroll
  for (int q = 0; q < 2; ++q) {
    const int s = tid + q * 512;
    srow[q] = s >> 3;
    scol[q] = (((s & 7) ^ (srow[q] & 7)) * 8);
  }

#pragma unroll
  for (int i = 0; i < 2; ++i)
#pragma unroll
    for (int r = 0; r < 16; ++r) acc[i][r] = 0.0f;

  // prologue: tile 0 -> buf0
  stg64(A, W, a0, b0, 0, m0, n0, srow, scol, tid);

  // 12 K-tiles of 64, pairs for static buffer pointers.
  // __syncthreads() emits s_waitcnt vmcnt(0) lgkmcnt(0) + s_barrier:
  // at each barrier exactly ONE stage is outstanding -> it is the precise
  // wait for the buffer about to be computed, and it has had a full
  // compute-phase in flight.
  for (int t = 0; t < 12; t += 2) {
    __syncthreads();                                    // drains stage(t)
    if (t + 1 < 12) stg64(A, W, a1, b1, (t + 1) * 64, m0, n0, srow, scol, tid);
    comp64(a0, b0, wr, wc, l31, hi, acc);               // tile t
    __syncthreads();                                    // drains stage(t+1)
    if (t + 2 < 12) stg64(A, W, a0, b0, (t + 2) * 64, m0, n0, srow, scol, tid);
    comp64(a1, b1, wr, wc, l31, hi, acc);               // tile t+1
  }
}

// Epilogue index helpers: with swapped operands,
//   C row (m) = m0 + wr + 32*i + l31
//   C col (n) = n0 + wc + (reg&3) + 8*(reg>>2) + 4*hi   (reg = 4*rr+q)

// Fused K/V/R GEMM. grid 4608 = chunk(4) x ntile(18) x mm(64), mm fastest
// (R0 order: L3 keeps the 12.5MB A-chunk resident across 18 n-passes).
__global__ __launch_bounds__(512) void gemm_kvr(
    const bf16* __restrict__ A, const bf16* __restrict__ Wcat,
    bf16* __restrict__ Kb, bf16* __restrict__ Vb, bf16* __restrict__ SRb)
{
  __shared__ __align__(16) bf16 lds[32768];   // 64 KB: 2 x (A 16KB + B 16KB)
  const int tid = threadIdx.x;
  const int bx = blockIdx.x;
  const int chunk = bx / 1152;
  const int rem   = bx % 1152;
  const int mm    = rem & 63;
  const int nt    = rem >> 6;
  const size_t m0 = (size_t)(chunk * 64 + mm) * 128;
  const int n0 = nt * 128;

  f32x16v acc[2];
  gemm_tile_acc(A, Wcat, lds, tid, m0, n0, acc);

  const int seg   = n0 / 768;
  const int ncol0 = n0 - seg * 768;
  bf16* __restrict__ dst = (seg == 0) ? Kb : (seg == 1) ? Vb : SRb;
  const int lane = tid & 63, wave = tid >> 6;
  const int l31 = lane & 31, hi = lane >> 5;
  const int wr = (wave >> 2) * 64, wc = (wave & 3) * 32;
#pragma unroll
  for (int i = 0; i < 2; ++i) {
    const size_t mrow = m0 + wr + 32 * i + l31;
    const int nb = ncol0 + wc + 4 * hi;
#pragma unroll
    for (int rr = 0; rr < 4; ++rr) {
      float v0 = acc[i][4 * rr + 0], v1 = acc[i][4 * rr + 1];
      float v2 = acc[i][4 * rr + 2], v3 = acc[i][4 * rr + 3];
      if (seg == 2) {
        v0 = 1.0f / (1.0f + __expf(-v0)); v1 = 1.0f / (1.0f + __expf(-v1));
        v2 = 1.0f / (1.0f + __expf(-v2)); v3 = 1.0f / (1.0f + __expf(-v3));
      }
      ushort4 pk = { bfraw(v0), bfraw(v1), bfraw(v2), bfraw(v3) };
      *(ushort4*)&dst[mrow * 768 + nb + 8 * rr] = pk;
    }
  }
}

// Output GEMM: fp32 out. grid 1536 = chunk(4) x ntile(6) x mm(64).
__global__ __launch_bounds__(512) void gemm_out(
    const bf16* __restrict__ A, const bf16* __restrict__ W,
    float* __restrict__ out)
{
  __shared__ __align__(16) bf16 lds[32768];
  const int tid = threadIdx.x;
  const int bx = blockIdx.x;
  const int chunk = bx / 384;
  const int rem   = bx % 384;
  const int mm    = rem & 63;
  const int nt    = rem >> 6;
  const size_t m0 = (size_t)(chunk * 64 + mm) * 128;
  const int n0 = nt * 128;

  f32x16v acc[2];
  gemm_tile_acc(A, W, lds, tid, m0, n0, acc);

  const int lane = tid & 63, wave = tid >> 6;
  const int l31 = lane & 31, hi = lane >> 5;
  const int wr = (wave >> 2) * 64, wc = (wave & 3) * 32;
#pragma unroll
  for (int i = 0; i < 2; ++i) {
    const size_t mrow = m0 + wr + 32 * i + l31;
    const int nb = n0 + wc + 4 * hi;
#pragma unroll
    for (int rr = 0; rr < 4; ++rr) {
      float4 pk = { acc[i][4 * rr + 0], acc[i][4 * rr + 1],
                    acc[i][4 * rr + 2], acc[i][4 * rr + 3] };
      *(float4*)&out[mrow * 768 + nb + 8 * rr] = pk;
    }
  }
}

// ------------------------------------------------------------ WKV chunk scan
// G=128 chunks of L=32. 4 channels/thread. State math fp32.
__global__ void wkv_phaseA(const bf16* __restrict__ K, const bf16* __restrict__ V,
                           const float* __restrict__ sd,
                           float* __restrict__ sA, float* __restrict__ sB, float* __restrict__ sP)
{
  const int idx = blockIdx.x * 256 + threadIdx.x;
  const int c4 = idx % 192;
  const int bg = idx / 192;
  const int g  = bg & 127;
  const int b  = bg >> 7;
  const int c0 = c4 * 4;
  float w[4], aa[4], bb[4], pp[4];
#pragma unroll
  for (int e = 0; e < 4; ++e) {
    w[e] = sd[c0 + e] * (1.0f / 4096.0f);
    aa[e] = 0.f; bb[e] = 0.f; pp[e] = -1e38f;
  }
  const size_t base = ((size_t)b * 4096 + (size_t)g * 32) * 768 + c0;
  const uint2* Kp = (const uint2*)(K + base);
  const uint2* Vp = (const uint2*)(V + base);
#pragma unroll 4
  for (int t = 0; t < 32; ++t) {
    const uint2 ku = Kp[(size_t)t * 192];
    const uint2 vu = Vp[(size_t)t * 192];
    const float kc[4] = { bflo(ku.x), bfhi(ku.x), bflo(ku.y), bfhi(ku.y) };
    const float vc[4] = { bflo(vu.x), bfhi(vu.x), bflo(vu.y), bfhi(vu.y) };
#pragma unroll
    for (int e = 0; e < 4; ++e) {
      const float ww2 = w[e] + pp[e];
      const float p2  = fmaxf(ww2, kc[e]);
      const float e1b = __expf(ww2 - p2);
      const float e2b = __expf(kc[e] - p2);
      aa[e] = e1b * aa[e] + e2b * vc[e];
      bb[e] = e1b * bb[e] + e2b;
      pp[e] = p2;
    }
  }
  const int o = g * 6144 + b * 768 + c0;
#pragma unroll
  for (int e = 0; e < 4; ++e) { sA[o + e] = aa[e]; sB[o + e] = bb[e]; sP[o + e] = pp[e]; }
}

// R6: LDS-staged serial scan. R5's Hillis-Steele had 24KB-stride gathers
// (64 cache lines per wave-load). Here: coalesced stage of 64 channels x
// 128 chunks into LDS (96 KB), then 64 threads scan serially in LDS
// (conflict-free: lanes read consecutive columns), coalesced writeback
// inline. 96 blocks x 256 threads.
__global__ __launch_bounds__(256) void wkv_phaseB(
    const float* __restrict__ sA, const float* __restrict__ sB,
    const float* __restrict__ sP,
    float* __restrict__ iA, float* __restrict__ iB, float* __restrict__ iP,
    const float* __restrict__ sd)
{
  __shared__ float la[128][64], lb[128][64], lp[128][64];
  const int bc0 = blockIdx.x * 64;
  const int tid = threadIdx.x;
  const int gr = tid >> 6;      // 0..3
  const int cc = tid & 63;
  for (int g0 = 0; g0 < 128; g0 += 4) {
    const int g = g0 + gr;
    const int o = g * 6144 + bc0 + cc;
    la[g][cc] = sA[o]; lb[g][cc] = sB[o]; lp[g][cc] = sP[o];
  }
  __syncthreads();
  if (tid < 64) {
    const int c = bc0 + tid;
    const float Lw = 32.0f * (sd[c % 768] * (1.0f / 4096.0f));
    float aa = 0.f, bb = 0.f, pp = -1e38f;
    for (int g = 0; g < 128; ++g) {
      const int o = g * 6144 + c;
      iA[o] = aa; iB[o] = bb; iP[o] = pp;             // state BEFORE chunk g
      const float lag = la[g][tid], lbg = lb[g][tid], lpg = lp[g][tid];
      const float pd = pp + Lw;
      const float pn = fmaxf(pd, lpg);
      const float e0 = __expf(pd - pn);
      const float e1 = __expf(lpg - pn);
      aa = e0 * aa + e1 * lag;
      bb = e0 * bb + e1 * lbg;
      pp = pn;
    }
  }
}

__global__ void wkv_phaseC(const bf16* __restrict__ K, const bf16* __restrict__ V,
                           const bf16* __restrict__ SR,
                           const float* __restrict__ iA, const float* __restrict__ iB,
                           const float* __restrict__ iP,
                           const float* __restrict__ sd, const float* __restrict__ sf,
                           bf16* __restrict__ RY)
{
  const int idx = blockIdx.x * 256 + threadIdx.x;
  const int c4 = idx % 192;
  const int bg = idx / 192;
  const int g  = bg & 127;
  const int b  = bg >> 7;
  const int c0 = c4 * 4;
  const int o = g * 6144 + b * 768 + c0;
  float w[4], u[4], aa[4], bb[4], pp[4];
#pragma unroll
  for (int e = 0; e < 4; ++e) {
    w[e] = sd[c0 + e] * (1.0f / 4096.0f);
    u[e] = sf[c0 + e] * (1.0f / 4096.0f);
    aa[e] = iA[o + e]; bb[e] = iB[o + e]; pp[e] = iP[o + e];
  }
  const size_t base = ((size_t)b * 4096 + (size_t)g * 32) * 768 + c0;
  const uint2* Kp = (const uint2*)(K + base);
  const uint2* Vp = (const uint2*)(V + base);
  const uint2* Sp = (const uint2*)(SR + base);
  uint2* Rp = (uint2*)(RY + base);
#pragma unroll 4
  for (int t = 0; t < 32; ++t) {
    const uint2 ku = Kp[(size_t)t * 192];
    const uint2 vu = Vp[(size_t)t * 192];
    const uint2 su = Sp[(size_t)t * 192];
    const float kc[4] = { bflo(ku.x), bfhi(ku.x), bflo(ku.y), bfhi(ku.y) };
    const float vc[4] = { bflo(vu.x), bfhi(vu.x), bflo(vu.y), bfhi(vu.y) };
    const float sc[4] = { bflo(su.x), bfhi(su.x), bflo(su.y), bfhi(su.y) };
    float y[4];
#pragma unroll
    for (int e = 0; e < 4; ++e) {
      const float ww = u[e] + kc[e];
      const float p  = fmaxf(pp[e], ww);
      const float e1 = __expf(pp[e] - p);
      const float e2 = __expf(ww - p);
      y[e] = (e1 * aa[e] + e2 * vc[e]) / (e1 * bb[e] + e2) * sc[e];
      const float ww2 = w[e] + pp[e];
      const float p2  = fmaxf(ww2, kc[e]);
      const float e1b = __expf(ww2 - p2);
      const float e2b = __expf(kc[e] - p2);
      aa[e] = e1b * aa[e] + e2b * vc[e];
      bb[e] = e1b * bb[e] + e2b;
      pp[e] = p2;
    }
    uint2 r; r.x = packbf(y[0], y[1]); r.y = packbf(y[2], y[3]);
    Rp[(size_t)t * 192] = r;
  }
}

// ---------------------------------------------------------------------------
extern "C" void kernel_launch(void* const* d_in, const int* in_sizes, int n_in,
                              void* d_out, int out_size, void* d_ws, size_t ws_size,
                              hipStream_t stream)
{
  const float* x  = (const float*)d_in[0];
  const float* wk = (const float*)d_in[1];
  const float* wv = (const float*)d_in[2];
  const float* wr = (const float*)d_in[3];
  const float* wo = (const float*)d_in[4];
  const float* sd = (const float*)d_in[5];
  const float* sf = (const float*)d_in[6];
  float* out = (float*)d_out;

  char* ws = (char*)d_ws;
  bf16*  x_bf  = (bf16*) (ws + 0);            // 25165824 * 2
  bf16*  wcat  = (bf16*) (ws + 50331648);     // 2304x768 bf16
  bf16*  wo_bf = (bf16*) (ws + 53870592);
  bf16*  Kb    = (bf16*) (ws + 55050240);     // 25165824 * 2 each
  bf16*  Vb    = (bf16*) (ws + 105381888);
  bf16*  SRb   = (bf16*) (ws + 155713536);
  float* sumA  = (float*)(ws + 206045184);    // 128*6144 floats (3 MB) each
  float* sumB  = (float*)(ws + 209190912);
  float* sumP  = (float*)(ws + 212336640);
  float* iniA  = (float*)(ws + 215482368);
  float* iniB  = (float*)(ws + 218628096);
  float* iniP  = (float*)(ws + 221773824);
  bf16*  ry_bf = x_bf;                        // x dead after gemm_kvr -> alias

  f2b4_all<<<26880, 256, 0, stream>>>(x, wk, wv, wr, wo, x_bf, wcat, wo_bf);

  gemm_kvr<<<4608, 512, 0, stream>>>(x_bf, wcat, Kb, Vb, SRb);

  wkv_phaseA<<<768, 256, 0, stream>>>(Kb, Vb, sd, sumA, sumB, sumP);
  wkv_phaseB<<<96, 256, 0, stream>>>(sumA, sumB, sumP, iniA, iniB, iniP, sd);
  wkv_phaseC<<<768, 256, 0, stream>>>(Kb, Vb, SRb, iniA, iniB, iniP, sd, sf, ry_bf);

  gemm_out<<<1536, 512, 0, stream>>>(ry_bf, wo_bf, out);
}

// Round 7
// 437.512 us; speedup vs baseline: 1.2208x; 1.0192x over previous
//
#include <hip/hip_runtime.h>
#include <hip/hip_bf16.h>

using bf16 = __hip_bfloat16;
typedef short bf16x8v  __attribute__((ext_vector_type(8)));
typedef float f32x16v  __attribute__((ext_vector_type(16)));

#define GLD_LDS16(g, l) __builtin_amdgcn_global_load_lds(                      \
    (const __attribute__((address_space(1))) void*)(g),                        \
    (__attribute__((address_space(3))) void*)(l), 16, 0, 0)

__device__ __forceinline__ float bflo(unsigned int u) {
  union { unsigned int i; float f; } c; c.i = u << 16; return c.f;
}
__device__ __forceinline__ float bfhi(unsigned int u) {
  union { unsigned int i; float f; } c; c.i = u & 0xffff0000u; return c.f;
}
__device__ __forceinline__ unsigned int packbf(float a, float b) {
  return (unsigned int)(__hip_bfloat16_raw(__float2bfloat16(a)).x) |
         ((unsigned int)(__hip_bfloat16_raw(__float2bfloat16(b)).x) << 16);
}
__device__ __forceinline__ unsigned short bfraw(float a) {
  return __hip_bfloat16_raw(__float2bfloat16(a)).x;
}

// ------------------------------------------------- all fp32->bf16 casts, one launch
__global__ void f2b4_all(const float* __restrict__ x,  const float* __restrict__ wk,
                         const float* __restrict__ wv, const float* __restrict__ wr,
                         const float* __restrict__ wo,
                         bf16* __restrict__ x_bf, bf16* __restrict__ wcat,
                         bf16* __restrict__ wo_bf) {
  int i = blockIdx.x * blockDim.x + threadIdx.x;
  const float* s; bf16* d; int idx;
  if (i < 6291456) { s = x; d = x_bf; idx = i; }
  else {
    int j = i - 6291456;
    int seg = j / 147456;
    idx = j - seg * 147456;
    if (seg == 0)      { s = wk; d = wcat; }
    else if (seg == 1) { s = wv; d = wcat + 589824; }
    else if (seg == 2) { s = wr; d = wcat + 1179648; }
    else               { s = wo; d = wo_bf; }
  }
  const float4 f = reinterpret_cast<const float4*>(s)[idx];
  struct B4 { bf16 a, b, c, d; };
  B4 o = { __float2bfloat16(f.x), __float2bfloat16(f.y),
           __float2bfloat16(f.z), __float2bfloat16(f.w) };
  reinterpret_cast<B4*>(d)[idx] = o;
}

// --------------------------------------------------------------- GEMM core
// R7: core IDENTICAL to R6 (8-wave, wave tile 64x32, BK=64 dbuf, granule-XOR
// swizzle, global_load_lds w=16, swapped-operand v_mfma_f32_32x32x16_bf16).
// CHANGE: epilogue now writes FULL CACHE LINES via an LDS transpose.
// Theory (R0-R6 invariance at 162-170us across occupancy 20-62%, reuse
// 1.33-2.67x, dbuf on/off): the old epilogue stored 16-B fragments per row
// (row stride 1536B); partial-line write misses trigger L2 read-for-
// ownership -> FETCH excess +62MB (116 measured vs 54 compulsory), RMW
// reads throttle L2/fabric regardless of loop structure. Fix: stage C-tile
// to LDS, stream out 64-lane x 16B CONTIGUOUS stores (4 rows x 256B/instr).
// Discriminator: FETCH_SIZE should drop to ~58MB.
// DON'T re-try: BK=32 dbuf (R4), 256^2 8-phase (R1), 256x128 wave tile
// (R3: occupancy cliff), XCD n-major remap (R2: fetch 112->160MB),
// occupancy-only changes (R5: 62% occ == 31% occ perf).
__device__ __forceinline__ void stg64(
    const bf16* __restrict__ A, const bf16* __restrict__ W,
    bf16* la, bf16* lb, int k0, size_t m0, int n0,
    const int srow[2], const int scol[2], int tid)
{
#pragma unroll
  for (int q = 0; q < 2; ++q) {
    GLD_LDS16(A + (m0 + srow[q]) * 768 + k0 + scol[q],
              &la[(size_t)(tid + q * 512) * 8]);
    GLD_LDS16(W + ((size_t)n0 + srow[q]) * 768 + k0 + scol[q],
              &lb[(size_t)(tid + q * 512) * 8]);
  }
}

__device__ __forceinline__ void comp64(
    const bf16* la, const bf16* lb, int wr, int wc, int l31, int hi,
    f32x16v acc[2])
{
#pragma unroll
  for (int ks = 0; ks < 4; ++ks) {           // k-steps of 16 within BK=64
    const int gl = ks * 2 + hi;              // element granule = k/8 (pre-swizzle)
    bf16x8v av[2], bv;
#pragma unroll
    for (int i = 0; i < 2; ++i) {
      const int ra = wr + 32 * i + l31;
      av[i] = *(const bf16x8v*)&la[ra * 64 + ((gl ^ (ra & 7)) * 8)];
    }
    {
      const int rb = wc + l31;
      bv = *(const bf16x8v*)&lb[rb * 64 + ((gl ^ (rb & 7)) * 8)];
    }
#pragma unroll
    for (int i = 0; i < 2; ++i)
      acc[i] = __builtin_amdgcn_mfma_f32_32x32x16_bf16(bv, av[i], acc[i], 0, 0, 0);
  }
}

__device__ __forceinline__ void gemm_tile_acc(
    const bf16* __restrict__ A, const bf16* __restrict__ W,
    bf16* lds, int tid, size_t m0, int n0, f32x16v acc[2])
{
  bf16* const a0 = lds;                 // each 128x64 bf16 = 16 KB
  bf16* const b0 = lds + 8192;
  bf16* const a1 = lds + 16384;
  bf16* const b1 = lds + 24576;

  const int lane = tid & 63;
  const int wave = tid >> 6;          // 0..7
  const int l31  = lane & 31;
  const int hi   = lane >> 5;
  const int wr   = (wave >> 2) * 64;  // 2 wave-rows x 64
  const int wc   = (wave & 3) * 32;   // 4 wave-cols x 32

  int srow[2], scol[2];
#pragma unroll
  for (int q = 0; q < 2; ++q) {
    const int s = tid + q * 512;
    srow[q] = s >> 3;
    scol[q] = (((s & 7) ^ (srow[q] & 7)) * 8);
  }

#pragma unroll
  for (int i = 0; i < 2; ++i)
#pragma unroll
    for (int r = 0; r < 16; ++r) acc[i][r] = 0.0f;

  // prologue: tile 0 -> buf0
  stg64(A, W, a0, b0, 0, m0, n0, srow, scol, tid);

  // 12 K-tiles of 64, pairs for static buffer pointers. __syncthreads()
  // emits vmcnt(0)+barrier: at each barrier exactly one stage outstanding,
  // and it has had a full compute-phase in flight.
  for (int t = 0; t < 12; t += 2) {
    __syncthreads();                                    // drains stage(t)
    if (t + 1 < 12) stg64(A, W, a1, b1, (t + 1) * 64, m0, n0, srow, scol, tid);
    comp64(a0, b0, wr, wc, l31, hi, acc);               // tile t
    __syncthreads();                                    // drains stage(t+1)
    if (t + 2 < 12) stg64(A, W, a0, b0, (t + 2) * 64, m0, n0, srow, scol, tid);
    comp64(a1, b1, wr, wc, l31, hi, acc);               // tile t+1
  }
}

// Epilogue index helpers: with swapped operands,
//   C row (m) = m0 + wr + 32*i + l31
//   C col (n) = n0 + wc + (reg&3) + 8*(reg>>2) + 4*hi   (reg = 4*rr+q)

// Fused K/V/R GEMM. grid 4608 = chunk(4) x ntile(18) x mm(64), mm fastest
// (R0 order: L3 keeps the 12.5MB A-chunk resident across 18 n-passes).
__global__ __launch_bounds__(512) void gemm_kvr(
    const bf16* __restrict__ A, const bf16* __restrict__ Wcat,
    bf16* __restrict__ Kb, bf16* __restrict__ Vb, bf16* __restrict__ SRb)
{
  __shared__ __align__(16) bf16 lds[32768];   // 64 KB: 2 x (A 16KB + B 16KB)
  const int tid = threadIdx.x;
  const int bx = blockIdx.x;
  const int chunk = bx / 1152;
  const int rem   = bx % 1152;
  const int mm    = rem & 63;
  const int nt    = rem >> 6;
  const size_t m0 = (size_t)(chunk * 64 + mm) * 128;
  const int n0 = nt * 128;

  f32x16v acc[2];
  gemm_tile_acc(A, Wcat, lds, tid, m0, n0, acc);

  const int seg   = n0 / 768;
  const int ncol0 = n0 - seg * 768;
  bf16* __restrict__ dst = (seg == 0) ? Kb : (seg == 1) ? Vb : SRb;
  const int lane = tid & 63, wave = tid >> 6;
  const int l31 = lane & 31, hi = lane >> 5;
  const int wr = (wave >> 2) * 64, wc = (wave & 3) * 32;

  // ---- full-line epilogue: acc -> LDS [128][136] bf16 -> contiguous stores
  __syncthreads();                 // all ds_reads of final buffers complete
  unsigned short* et = (unsigned short*)lds;
#pragma unroll
  for (int i = 0; i < 2; ++i) {
    const int row_l = wr + 32 * i + l31;
#pragma unroll
    for (int rr = 0; rr < 4; ++rr) {
      float v0 = acc[i][4 * rr + 0], v1 = acc[i][4 * rr + 1];
      float v2 = acc[i][4 * rr + 2], v3 = acc[i][4 * rr + 3];
      if (seg == 2) {
        v0 = 1.0f / (1.0f + __expf(-v0)); v1 = 1.0f / (1.0f + __expf(-v1));
        v2 = 1.0f / (1.0f + __expf(-v2)); v3 = 1.0f / (1.0f + __expf(-v3));
      }
      ushort4 pk = { bfraw(v0), bfraw(v1), bfraw(v2), bfraw(v3) };
      *(ushort4*)&et[row_l * 136 + wc + 4 * hi + 8 * rr] = pk;
    }
  }
  __syncthreads();
  // stream out: 2048 chunks of 16B; per instr 64 lanes = 4 rows x 256B
#pragma unroll
  for (int it = 0; it < 4; ++it) {
    const int ci = it * 512 + tid;
    const int r  = ci >> 4;
    const int c8 = (ci & 15) * 8;
    const uint4 w = *(const uint4*)&et[r * 136 + c8];
    *(uint4*)&dst[(m0 + r) * 768 + ncol0 + c8] = w;
  }
}

// Output GEMM: fp32 out. grid 1536 = chunk(4) x ntile(6) x mm(64).
__global__ __launch_bounds__(512) void gemm_out(
    const bf16* __restrict__ A, const bf16* __restrict__ W,
    float* __restrict__ out)
{
  __shared__ __align__(16) bf16 lds[32768];
  const int tid = threadIdx.x;
  const int bx = blockIdx.x;
  const int chunk = bx / 384;
  const int rem   = bx % 384;
  const int mm    = rem & 63;
  const int nt    = rem >> 6;
  const size_t m0 = (size_t)(chunk * 64 + mm) * 128;
  const int n0 = nt * 128;

  f32x16v acc[2];
  gemm_tile_acc(A, W, lds, tid, m0, n0, acc);

  const int lane = tid & 63, wave = tid >> 6;
  const int l31 = lane & 31, hi = lane >> 5;
  const int wr = (wave >> 2) * 64, wc = (wave & 3) * 32;

  // ---- full-line epilogue: two fp32 half-tiles [64][136] through LDS
  __syncthreads();
  float* ef = (float*)lds;
  for (int h = 0; h < 2; ++h) {
    if ((wave >> 2) == h) {
#pragma unroll
      for (int i = 0; i < 2; ++i) {
        const int row_l = 32 * i + l31;
#pragma unroll
        for (int rr = 0; rr < 4; ++rr) {
          float4 pk = { acc[i][4 * rr + 0], acc[i][4 * rr + 1],
                        acc[i][4 * rr + 2], acc[i][4 * rr + 3] };
          *(float4*)&ef[row_l * 136 + wc + 4 * hi + 8 * rr] = pk;
        }
      }
    }
    __syncthreads();
    // 2048 chunks of 16B; per instr 64 lanes = 2 rows x 512B contiguous
#pragma unroll
    for (int it = 0; it < 4; ++it) {
      const int ci = it * 512 + tid;
      const int r  = ci >> 5;
      const int c4 = (ci & 31) * 4;
      const float4 w = *(const float4*)&ef[r * 136 + c4];
      *(float4*)&out[(m0 + h * 64 + r) * 768 + n0 + c4] = w;
    }
    __syncthreads();
  }
}

// ------------------------------------------------------------ WKV chunk scan
// G=128 chunks of L=32. 4 channels/thread. State math fp32.
__global__ void wkv_phaseA(const bf16* __restrict__ K, const bf16* __restrict__ V,
                           const float* __restrict__ sd,
                           float* __restrict__ sA, float* __restrict__ sB, float* __restrict__ sP)
{
  const int idx = blockIdx.x * 256 + threadIdx.x;
  const int c4 = idx % 192;
  const int bg = idx / 192;
  const int g  = bg & 127;
  const int b  = bg >> 7;
  const int c0 = c4 * 4;
  float w[4], aa[4], bb[4], pp[4];
#pragma unroll
  for (int e = 0; e < 4; ++e) {
    w[e] = sd[c0 + e] * (1.0f / 4096.0f);
    aa[e] = 0.f; bb[e] = 0.f; pp[e] = -1e38f;
  }
  const size_t base = ((size_t)b * 4096 + (size_t)g * 32) * 768 + c0;
  const uint2* Kp = (const uint2*)(K + base);
  const uint2* Vp = (const uint2*)(V + base);
#pragma unroll 4
  for (int t = 0; t < 32; ++t) {
    const uint2 ku = Kp[(size_t)t * 192];
    const uint2 vu = Vp[(size_t)t * 192];
    const float kc[4] = { bflo(ku.x), bfhi(ku.x), bflo(ku.y), bfhi(ku.y) };
    const float vc[4] = { bflo(vu.x), bfhi(vu.x), bflo(vu.y), bfhi(vu.y) };
#pragma unroll
    for (int e = 0; e < 4; ++e) {
      const float ww2 = w[e] + pp[e];
      const float p2  = fmaxf(ww2, kc[e]);
      const float e1b = __expf(ww2 - p2);
      const float e2b = __expf(kc[e] - p2);
      aa[e] = e1b * aa[e] + e2b * vc[e];
      bb[e] = e1b * bb[e] + e2b;
      pp[e] = p2;
    }
  }
  const int o = g * 6144 + b * 768 + c0;
#pragma unroll
  for (int e = 0; e < 4; ++e) { sA[o + e] = aa[e]; sB[o + e] = bb[e]; sP[o + e] = pp[e]; }
}

// R6 phaseB (kept): coalesced LDS-staged serial scan. 96 blocks x 256.
__global__ __launch_bounds__(256) void wkv_phaseB(
    const float* __restrict__ sA, const float* __restrict__ sB,
    const float* __restrict__ sP,
    float* __restrict__ iA, float* __restrict__ iB, float* __restrict__ iP,
    const float* __restrict__ sd)
{
  __shared__ float la[128][64], lb[128][64], lp[128][64];
  const int bc0 = blockIdx.x * 64;
  const int tid = threadIdx.x;
  const int gr = tid >> 6;      // 0..3
  const int cc = tid & 63;
  for (int g0 = 0; g0 < 128; g0 += 4) {
    const int g = g0 + gr;
    const int o = g * 6144 + bc0 + cc;
    la[g][cc] = sA[o]; lb[g][cc] = sB[o]; lp[g][cc] = sP[o];
  }
  __syncthreads();
  if (tid < 64) {
    const int c = bc0 + tid;
    const float Lw = 32.0f * (sd[c % 768] * (1.0f / 4096.0f));
    float aa = 0.f, bb = 0.f, pp = -1e38f;
    for (int g = 0; g < 128; ++g) {
      const int o = g * 6144 + c;
      iA[o] = aa; iB[o] = bb; iP[o] = pp;             // state BEFORE chunk g
      const float lag = la[g][tid], lbg = lb[g][tid], lpg = lp[g][tid];
      const float pd = pp + Lw;
      const float pn = fmaxf(pd, lpg);
      const float e0 = __expf(pd - pn);
      const float e1 = __expf(lpg - pn);
      aa = e0 * aa + e1 * lag;
      bb = e0 * bb + e1 * lbg;
      pp = pn;
    }
  }
}

__global__ void wkv_phaseC(const bf16* __restrict__ K, const bf16* __restrict__ V,
                           const bf16* __restrict__ SR,
                           const float* __restrict__ iA, const float* __restrict__ iB,
                           const float* __restrict__ iP,
                           const float* __restrict__ sd, const float* __restrict__ sf,
                           bf16* __restrict__ RY)
{
  const int idx = blockIdx.x * 256 + threadIdx.x;
  const int c4 = idx % 192;
  const int bg = idx / 192;
  const int g  = bg & 127;
  const int b  = bg >> 7;
  const int c0 = c4 * 4;
  const int o = g * 6144 + b * 768 + c0;
  float w[4], u[4], aa[4], bb[4], pp[4];
#pragma unroll
  for (int e = 0; e < 4; ++e) {
    w[e] = sd[c0 + e] * (1.0f / 4096.0f);
    u[e] = sf[c0 + e] * (1.0f / 4096.0f);
    aa[e] = iA[o + e]; bb[e] = iB[o + e]; pp[e] = iP[o + e];
  }
  const size_t base = ((size_t)b * 4096 + (size_t)g * 32) * 768 + c0;
  const uint2* Kp = (const uint2*)(K + base);
  const uint2* Vp = (const uint2*)(V + base);
  const uint2* Sp = (const uint2*)(SR + base);
  uint2* Rp = (uint2*)(RY + base);
#pragma unroll 4
  for (int t = 0; t < 32; ++t) {
    const uint2 ku = Kp[(size_t)t * 192];
    const uint2 vu = Vp[(size_t)t * 192];
    const uint2 su = Sp[(size_t)t * 192];
    const float kc[4] = { bflo(ku.x), bfhi(ku.x), bflo(ku.y), bfhi(ku.y) };
    const float vc[4] = { bflo(vu.x), bfhi(vu.x), bflo(vu.y), bfhi(vu.y) };
    const float sc[4] = { bflo(su.x), bfhi(su.x), bflo(su.y), bfhi(su.y) };
    float y[4];
#pragma unroll
    for (int e = 0; e < 4; ++e) {
      const float ww = u[e] + kc[e];
      const float p  = fmaxf(pp[e], ww);
      const float e1 = __expf(pp[e] - p);
      const float e2 = __expf(ww - p);
      y[e] = (e1 * aa[e] + e2 * vc[e]) / (e1 * bb[e] + e2) * sc[e];
      const float ww2 = w[e] + pp[e];
      const float p2  = fmaxf(ww2, kc[e]);
      const float e1b = __expf(ww2 - p2);
      const float e2b = __expf(kc[e] - p2);
      aa[e] = e1b * aa[e] + e2b * vc[e];
      bb[e] = e1b * bb[e] + e2b;
      pp[e] = p2;
    }
    uint2 r; r.x = packbf(y[0], y[1]); r.y = packbf(y[2], y[3]);
    Rp[(size_t)t * 192] = r;
  }
}

// ---------------------------------------------------------------------------
extern "C" void kernel_launch(void* const* d_in, const int* in_sizes, int n_in,
                              void* d_out, int out_size, void* d_ws, size_t ws_size,
                              hipStream_t stream)
{
  const float* x  = (const float*)d_in[0];
  const float* wk = (const float*)d_in[1];
  const float* wv = (const float*)d_in[2];
  const float* wr = (const float*)d_in[3];
  const float* wo = (const float*)d_in[4];
  const float* sd = (const float*)d_in[5];
  const float* sf = (const float*)d_in[6];
  float* out = (float*)d_out;

  char* ws = (char*)d_ws;
  bf16*  x_bf  = (bf16*) (ws + 0);            // 25165824 * 2
  bf16*  wcat  = (bf16*) (ws + 50331648);     // 2304x768 bf16
  bf16*  wo_bf = (bf16*) (ws + 53870592);
  bf16*  Kb    = (bf16*) (ws + 55050240);     // 25165824 * 2 each
  bf16*  Vb    = (bf16*) (ws + 105381888);
  bf16*  SRb   = (bf16*) (ws + 155713536);
  float* sumA  = (float*)(ws + 206045184);    // 128*6144 floats (3 MB) each
  float* sumB  = (float*)(ws + 209190912);
  float* sumP  = (float*)(ws + 212336640);
  float* iniA  = (float*)(ws + 215482368);
  float* iniB  = (float*)(ws + 218628096);
  float* iniP  = (float*)(ws + 221773824);
  bf16*  ry_bf = x_bf;                        // x dead after gemm_kvr -> alias

  f2b4_all<<<26880, 256, 0, stream>>>(x, wk, wv, wr, wo, x_bf, wcat, wo_bf);

  gemm_kvr<<<4608, 512, 0, stream>>>(x_bf, wcat, Kb, Vb, SRb);

  wkv_phaseA<<<768, 256, 0, stream>>>(Kb, Vb, sd, sumA, sumB, sumP);
  wkv_phaseB<<<96, 256, 0, stream>>>(sumA, sumB, sumP, iniA, iniB, iniP, sd);
  wkv_phaseC<<<768, 256, 0, stream>>>(Kb, Vb, SRb, iniA, iniB, iniP, sd, sf, ry_bf);

  gemm_out<<<1536, 512, 0, stream>>>(ry_bf, wo_bf, out);
}